// Round 1
// baseline (889.530 us; speedup 1.0000x reference)
//
#include <hip/hip_runtime.h>
#include <math.h>

// 3-layer GAT, N=50000 nodes, E=800000 edges (+N self loops).
// Layers: (2 -> 4x64 concat) -> (256 -> 4x64 concat) -> (256 -> 1x2 mean), ReLU after each.

__device__ __forceinline__ float wred_sum(float v){
  #pragma unroll
  for (int m = 32; m > 0; m >>= 1) v += __shfl_xor(v, m, 64);
  return v;
}
__device__ __forceinline__ float wred_max(float v){
  #pragma unroll
  for (int m = 32; m > 0; m >>= 1) v = fmaxf(v, __shfl_xor(v, m, 64));
  return v;
}

// ---------------- CSR build ----------------
__global__ __launch_bounds__(256) void k_init_deg(int* deg, int N){
  int i = blockIdx.x * 256 + threadIdx.x;
  if (i < N) deg[i] = 1;  // self loop
}

__global__ __launch_bounds__(256) void k_hist(const int* __restrict__ dst, int E, int* deg){
  int e = blockIdx.x * 256 + threadIdx.x;
  if (e < E) atomicAdd(&deg[dst[e]], 1);
}

__global__ __launch_bounds__(1024) void k_scan(const int* __restrict__ deg, int* rowptr, int N){
  __shared__ int sb[1024];
  int t = threadIdx.x;
  int chunk = (N + 1023) >> 10;
  int lo = t * chunk, hi = min(lo + chunk, N);
  int s = 0;
  for (int i = lo; i < hi; i++) s += deg[i];
  sb[t] = s;
  __syncthreads();
  for (int off = 1; off < 1024; off <<= 1){
    int v = (t >= off) ? sb[t - off] : 0;
    __syncthreads();
    sb[t] += v;
    __syncthreads();
  }
  int run = (t == 0) ? 0 : sb[t - 1];
  for (int i = lo; i < hi; i++){ rowptr[i] = run; run += deg[i]; }
  if (t == 1023) rowptr[N] = sb[1023];
}

__global__ __launch_bounds__(256) void k_selfloop(const int* __restrict__ rowptr, int* ssrc, int* cursor, int N){
  int i = blockIdx.x * 256 + threadIdx.x;
  if (i < N){ int p = rowptr[i]; ssrc[p] = i; cursor[i] = p + 1; }
}

__global__ __launch_bounds__(256) void k_scatter(const int* __restrict__ src, const int* __restrict__ dst,
                                                 int E, int* cursor, int* ssrc){
  int e = blockIdx.x * 256 + threadIdx.x;
  if (e < E){ int p = atomicAdd(&cursor[dst[e]], 1); ssrc[p] = src[e]; }
}

// ---------------- Layer 0 feature: h0 = x @ W0 (K=2), + e_src/e_dst ----------------
__global__ __launch_bounds__(256) void k_l0_feat(const float* __restrict__ X, const float* __restrict__ W,
                                                 const float* __restrict__ as_, const float* __restrict__ ad_,
                                                 float* __restrict__ Hh, float* __restrict__ ES,
                                                 float* __restrict__ ED, int N){
  int j = threadIdx.x;
  int n0 = blockIdx.x * 16;
  float w0 = W[j], w1 = W[256 + j];
  float asj = as_[j], adj = ad_[j];
  int head = j >> 6, lane = j & 63;
  #pragma unroll
  for (int i = 0; i < 16; i++){
    int n = n0 + i;
    if (n >= N) break;
    float x0 = X[2*n], x1 = X[2*n + 1];
    float hv = fmaf(x0, w0, x1 * w1);
    Hh[(size_t)n * 256 + j] = hv;
    float ps = wred_sum(hv * asj);
    float pd = wred_sum(hv * adj);
    if (lane == 0){ ES[n*4 + head] = ps; ED[n*4 + head] = pd; }
  }
}

// ---------------- Layer 1 feature: h1 = x1 @ W1 (256x256), + e_src/e_dst ----------------
__global__ __launch_bounds__(256) void k_l1_feat(const float* __restrict__ X, const float* __restrict__ W,
                                                 const float* __restrict__ as_, const float* __restrict__ ad_,
                                                 float* __restrict__ Hh, float* __restrict__ ES,
                                                 float* __restrict__ ED, int N){
  __shared__ float xs[16][260];
  int t = threadIdx.x;
  int n0 = blockIdx.x * 16;
  {
    int n = t >> 4, c4 = t & 15;
    if (n0 + n < N){
      const float4* Xr = (const float4*)(X + (size_t)(n0 + n) * 256);
      #pragma unroll
      for (int r = 0; r < 4; r++){
        float4 v = Xr[c4 + 16*r];
        *(float4*)&xs[n][(c4 + 16*r) * 4] = v;
      }
    }
  }
  __syncthreads();
  float acc[16];
  #pragma unroll
  for (int i = 0; i < 16; i++) acc[i] = 0.f;
  const float* Wj = W + t;
  for (int kb = 0; kb < 64; kb++){
    float wv0 = Wj[(kb*4 + 0) * 256];
    float wv1 = Wj[(kb*4 + 1) * 256];
    float wv2 = Wj[(kb*4 + 2) * 256];
    float wv3 = Wj[(kb*4 + 3) * 256];
    #pragma unroll
    for (int i = 0; i < 16; i++){
      float4 xv = *(const float4*)&xs[i][kb*4];
      acc[i] = fmaf(xv.x, wv0, acc[i]);
      acc[i] = fmaf(xv.y, wv1, acc[i]);
      acc[i] = fmaf(xv.z, wv2, acc[i]);
      acc[i] = fmaf(xv.w, wv3, acc[i]);
    }
  }
  int head = t >> 6, lane = t & 63;
  float asj = as_[t], adj = ad_[t];
  #pragma unroll
  for (int i = 0; i < 16; i++){
    int n = n0 + i;
    if (n >= N) break;
    Hh[(size_t)n * 256 + t] = acc[i];
    float ps = wred_sum(acc[i] * asj);
    float pd = wred_sum(acc[i] * adj);
    if (lane == 0){ ES[n*4 + head] = ps; ED[n*4 + head] = pd; }
  }
}

// ---------------- Edge phase layers 0/1: segment softmax + aggregate, H=4, O=64 ----------------
__global__ __launch_bounds__(256) void k_edge01(const float* __restrict__ Hh, const float* __restrict__ ES,
                                                const float* __restrict__ ED, const int* __restrict__ rowptr,
                                                const int* __restrict__ ssrc, const float* __restrict__ bias,
                                                float* __restrict__ Out, int N){
  int n = blockIdx.x;
  int head = threadIdx.x >> 6, lane = threadIdx.x & 63;
  int start = rowptr[n], deg = rowptr[n + 1] - start;
  float ed = ED[n*4 + head];
  float m = -3.0e38f;
  for (int i = lane; i < deg; i += 64){
    int s = ssrc[start + i];
    float a = ES[s*4 + head] + ed;
    a = fmaxf(a, 0.2f * a);           // leaky relu 0.2
    m = fmaxf(m, a);
  }
  m = wred_max(m);
  float den = 0.f, acc = 0.f;
  for (int base = 0; base < deg; base += 64){
    int cl = min(deg - base, 64);
    float wt = 0.f; int s = 0;
    if (lane < cl){
      s = ssrc[start + base + lane];
      float a = ES[s*4 + head] + ed;
      a = fmaxf(a, 0.2f * a);
      wt = __expf(a - m);
    }
    den += wt;
    for (int j = 0; j < cl; j++){
      float wj = __shfl(wt, j, 64);
      int   sj = __shfl(s,  j, 64);
      acc = fmaf(wj, Hh[(size_t)sj * 256 + head*64 + lane], acc);
    }
  }
  den = wred_sum(den);
  float o = acc / (den + 1e-16f) + bias[head*64 + lane];
  Out[(size_t)n * 256 + head*64 + lane] = fmaxf(o, 0.f);   // relu
}

// ---------------- Layer 2 feature: h2 = x2 @ W2 (256->2), + scalar e ----------------
__global__ __launch_bounds__(256) void k_l2_feat(const float* __restrict__ X, const float* __restrict__ W,
                                                 const float* __restrict__ as_, const float* __restrict__ ad_,
                                                 float* __restrict__ H2, float* __restrict__ ES,
                                                 float* __restrict__ ED, int N){
  int wave = threadIdx.x >> 6, lane = threadIdx.x & 63;
  int n = blockIdx.x * 4 + wave;
  if (n >= N) return;
  const float* xr = X + (size_t)n * 256;
  float p0 = 0.f, p1 = 0.f;
  #pragma unroll
  for (int c = 0; c < 4; c++){
    int k = lane + 64*c;
    float xv = xr[k];
    p0 = fmaf(xv, W[2*k],     p0);
    p1 = fmaf(xv, W[2*k + 1], p1);
  }
  p0 = wred_sum(p0); p1 = wred_sum(p1);
  if (lane == 0){
    H2[n*2] = p0; H2[n*2 + 1] = p1;
    ES[n] = p0*as_[0] + p1*as_[1];
    ED[n] = p0*ad_[0] + p1*ad_[1];
  }
}

// ---------------- Edge phase layer 2: H=1, O=2, mean over heads == identity ----------------
__global__ __launch_bounds__(256) void k_edge2(const float* __restrict__ H2, const float* __restrict__ ES,
                                               const float* __restrict__ ED, const int* __restrict__ rowptr,
                                               const int* __restrict__ ssrc, const float* __restrict__ bias,
                                               float* __restrict__ Out, int N){
  int wave = threadIdx.x >> 6, lane = threadIdx.x & 63;
  int n = blockIdx.x * 4 + wave;
  if (n >= N) return;
  int start = rowptr[n], deg = rowptr[n + 1] - start;
  float ed = ED[n];
  float m = -3.0e38f;
  for (int i = lane; i < deg; i += 64){
    int s = ssrc[start + i];
    float a = ES[s] + ed; a = fmaxf(a, 0.2f * a);
    m = fmaxf(m, a);
  }
  m = wred_max(m);
  float den = 0.f, a0 = 0.f, a1 = 0.f;
  for (int i = lane; i < deg; i += 64){
    int s = ssrc[start + i];
    float a = ES[s] + ed; a = fmaxf(a, 0.2f * a);
    float w = __expf(a - m);
    den += w;
    a0 = fmaf(w, H2[s*2],     a0);
    a1 = fmaf(w, H2[s*2 + 1], a1);
  }
  den = wred_sum(den); a0 = wred_sum(a0); a1 = wred_sum(a1);
  if (lane == 0){
    float inv = 1.f / (den + 1e-16f);
    Out[n*2]     = fmaxf(a0 * inv + bias[0], 0.f);
    Out[n*2 + 1] = fmaxf(a1 * inv + bias[1], 0.f);
  }
}

extern "C" void kernel_launch(void* const* d_in, const int* in_sizes, int n_in,
                              void* d_out, int out_size, void* d_ws, size_t ws_size,
                              hipStream_t stream) {
  const float* x   = (const float*)d_in[0];
  const int*   ei  = (const int*)  d_in[1];
  const float* W0  = (const float*)d_in[2];
  const float* as0 = (const float*)d_in[3];
  const float* ad0 = (const float*)d_in[4];
  const float* b0  = (const float*)d_in[5];
  const float* W1  = (const float*)d_in[6];
  const float* as1 = (const float*)d_in[7];
  const float* ad1 = (const float*)d_in[8];
  const float* b1  = (const float*)d_in[9];
  const float* W2  = (const float*)d_in[10];
  const float* as2 = (const float*)d_in[11];
  const float* ad2 = (const float*)d_in[12];
  const float* b2  = (const float*)d_in[13];

  int N = in_sizes[0] / 2;
  int E = in_sizes[1] / 2;
  const int* src = ei;
  const int* dst = ei + E;

  char* ws = (char*)d_ws;
  size_t off = 0;
  auto alc = [&](size_t bytes){ size_t o = off; off += (bytes + 255) & ~(size_t)255; return o; };
  int*   deg    = (int*)  (ws + alc((size_t)N * 4));
  int*   rowptr = (int*)  (ws + alc((size_t)(N + 1) * 4));
  int*   cursor = (int*)  (ws + alc((size_t)N * 4));
  int*   ssrc   = (int*)  (ws + alc((size_t)(E + N) * 4));
  float* bufA   = (float*)(ws + alc((size_t)N * 256 * 4));
  float* bufB   = (float*)(ws + alc((size_t)N * 256 * 4));
  float* es0    = (float*)(ws + alc((size_t)N * 4 * 4));
  float* ed0    = (float*)(ws + alc((size_t)N * 4 * 4));
  float* es1    = (float*)(ws + alc((size_t)N * 4 * 4));
  float* ed1    = (float*)(ws + alc((size_t)N * 4 * 4));
  float* h2     = (float*)(ws + alc((size_t)N * 2 * 4));
  float* es2    = (float*)(ws + alc((size_t)N * 4));
  float* ed2    = (float*)(ws + alc((size_t)N * 4));
  float* out    = (float*)d_out;

  // CSR build (edge topology shared by all 3 layers)
  k_init_deg<<<(N + 255)/256, 256, 0, stream>>>(deg, N);
  k_hist    <<<(E + 255)/256, 256, 0, stream>>>(dst, E, deg);
  k_scan    <<<1, 1024, 0, stream>>>(deg, rowptr, N);
  k_selfloop<<<(N + 255)/256, 256, 0, stream>>>(rowptr, ssrc, cursor, N);
  k_scatter <<<(E + 255)/256, 256, 0, stream>>>(src, dst, E, cursor, ssrc);

  // Layer 0: 2 -> 4x64 concat, relu
  k_l0_feat<<<(N + 15)/16, 256, 0, stream>>>(x, W0, as0, ad0, bufA, es0, ed0, N);
  k_edge01 <<<N, 256, 0, stream>>>(bufA, es0, ed0, rowptr, ssrc, b0, bufB, N);

  // Layer 1: 256 -> 4x64 concat, relu
  k_l1_feat<<<(N + 15)/16, 256, 0, stream>>>(bufB, W1, as1, ad1, bufA, es1, ed1, N);
  k_edge01 <<<N, 256, 0, stream>>>(bufA, es1, ed1, rowptr, ssrc, b1, bufB, N);

  // Layer 2: 256 -> 2, mean over 1 head, relu
  k_l2_feat<<<(N + 3)/4, 256, 0, stream>>>(bufB, W2, as2, ad2, h2, es2, ed2, N);
  k_edge2  <<<(N + 3)/4, 256, 0, stream>>>(h2, es2, ed2, rowptr, ssrc, b2, out, N);
}

// Round 3
// 698.855 us; speedup vs baseline: 1.2728x; 1.2728x over previous
//
#include <hip/hip_runtime.h>
#include <math.h>

// 3-layer GAT, N=50000 nodes, E=800000 edges (+N self loops).
// Layers: (2 -> 4x64 concat) -> (256 -> 4x64 concat) -> (256 -> 1x2 mean), ReLU after each.

__device__ __forceinline__ float wred_sum(float v){
  #pragma unroll
  for (int m = 32; m > 0; m >>= 1) v += __shfl_xor(v, m, 64);
  return v;
}
__device__ __forceinline__ float wred_max(float v){
  #pragma unroll
  for (int m = 32; m > 0; m >>= 1) v = fmaxf(v, __shfl_xor(v, m, 64));
  return v;
}

// ---------------- CSR build ----------------
__global__ __launch_bounds__(256) void k_init_deg(int* deg, int N){
  int i = blockIdx.x * 256 + threadIdx.x;
  if (i < N) deg[i] = 1;  // self loop
}

__global__ __launch_bounds__(256) void k_hist(const int* __restrict__ dst, int E, int* deg){
  int e = blockIdx.x * 256 + threadIdx.x;
  if (e < E) atomicAdd(&deg[dst[e]], 1);
}

__global__ __launch_bounds__(1024) void k_scan(const int* __restrict__ deg, int* rowptr, int N){
  __shared__ int sb[1024];
  int t = threadIdx.x;
  int chunk = (N + 1023) >> 10;
  int lo = t * chunk, hi = min(lo + chunk, N);
  int s = 0;
  for (int i = lo; i < hi; i++) s += deg[i];
  sb[t] = s;
  __syncthreads();
  for (int off = 1; off < 1024; off <<= 1){
    int v = (t >= off) ? sb[t - off] : 0;
    __syncthreads();
    sb[t] += v;
    __syncthreads();
  }
  int run = (t == 0) ? 0 : sb[t - 1];
  for (int i = lo; i < hi; i++){ rowptr[i] = run; run += deg[i]; }
  if (t == 1023) rowptr[N] = sb[1023];
}

__global__ __launch_bounds__(256) void k_selfloop(const int* __restrict__ rowptr, int* ssrc, int* cursor, int N){
  int i = blockIdx.x * 256 + threadIdx.x;
  if (i < N){ int p = rowptr[i]; ssrc[p] = i; cursor[i] = p + 1; }
}

__global__ __launch_bounds__(256) void k_scatter(const int* __restrict__ src, const int* __restrict__ dst,
                                                 int E, int* cursor, int* ssrc){
  int e = blockIdx.x * 256 + threadIdx.x;
  if (e < E){ int p = atomicAdd(&cursor[dst[e]], 1); ssrc[p] = src[e]; }
}

// ---------------- Layer 0 feature: h0 = x @ W0 (K=2), + e_src/e_dst ----------------
__global__ __launch_bounds__(256) void k_l0_feat(const float* __restrict__ X, const float* __restrict__ W,
                                                 const float* __restrict__ as_, const float* __restrict__ ad_,
                                                 float* __restrict__ Hh, float* __restrict__ ES,
                                                 float* __restrict__ ED, int N){
  int j = threadIdx.x;
  int n0 = blockIdx.x * 16;
  float w0 = W[j], w1 = W[256 + j];
  float asj = as_[j], adj = ad_[j];
  int head = j >> 6, lane = j & 63;
  #pragma unroll
  for (int i = 0; i < 16; i++){
    int n = n0 + i;
    if (n >= N) break;
    float x0 = X[2*n], x1 = X[2*n + 1];
    float hv = fmaf(x0, w0, x1 * w1);
    Hh[(size_t)n * 256 + j] = hv;
    float ps = wred_sum(hv * asj);
    float pd = wred_sum(hv * adj);
    if (lane == 0){ ES[n*4 + head] = ps; ED[n*4 + head] = pd; }
  }
}

// ---------------- Layer 1 feature: h1 = x1 @ W1 (256x256), + e_src/e_dst ----------------
__global__ __launch_bounds__(256) void k_l1_feat(const float* __restrict__ X, const float* __restrict__ W,
                                                 const float* __restrict__ as_, const float* __restrict__ ad_,
                                                 float* __restrict__ Hh, float* __restrict__ ES,
                                                 float* __restrict__ ED, int N){
  __shared__ float xs[16][260];
  int t = threadIdx.x;
  int n0 = blockIdx.x * 16;
  {
    int n = t >> 4, c4 = t & 15;
    if (n0 + n < N){
      const float4* Xr = (const float4*)(X + (size_t)(n0 + n) * 256);
      #pragma unroll
      for (int r = 0; r < 4; r++){
        float4 v = Xr[c4 + 16*r];
        *(float4*)&xs[n][(c4 + 16*r) * 4] = v;
      }
    }
  }
  __syncthreads();
  float acc[16];
  #pragma unroll
  for (int i = 0; i < 16; i++) acc[i] = 0.f;
  const float* Wj = W + t;
  for (int kb = 0; kb < 64; kb++){
    float wv0 = Wj[(kb*4 + 0) * 256];
    float wv1 = Wj[(kb*4 + 1) * 256];
    float wv2 = Wj[(kb*4 + 2) * 256];
    float wv3 = Wj[(kb*4 + 3) * 256];
    #pragma unroll
    for (int i = 0; i < 16; i++){
      float4 xv = *(const float4*)&xs[i][kb*4];
      acc[i] = fmaf(xv.x, wv0, acc[i]);
      acc[i] = fmaf(xv.y, wv1, acc[i]);
      acc[i] = fmaf(xv.z, wv2, acc[i]);
      acc[i] = fmaf(xv.w, wv3, acc[i]);
    }
  }
  int head = t >> 6, lane = t & 63;
  float asj = as_[t], adj = ad_[t];
  #pragma unroll
  for (int i = 0; i < 16; i++){
    int n = n0 + i;
    if (n >= N) break;
    Hh[(size_t)n * 256 + t] = acc[i];
    float ps = wred_sum(acc[i] * asj);
    float pd = wred_sum(acc[i] * adj);
    if (lane == 0){ ES[n*4 + head] = ps; ED[n*4 + head] = pd; }
  }
}

// ---------------- Edge phase layers 0/1: one WAVE per dst node, all 4 heads ----------------
// lane l covers output columns [4l, 4l+3]; head(l) = l>>4. ES/ED are [n][4] float4.
// LDS weight exchange is synchronized with __syncthreads over a BLOCK-UNIFORM
// chunk count (max over the block's 4 nodes) -- no inline-asm fences.
__global__ __launch_bounds__(256) void k_edge01(const float* __restrict__ Hh, const float* __restrict__ ES,
                                                const float* __restrict__ ED, const int* __restrict__ rowptr,
                                                const int* __restrict__ ssrc, const float* __restrict__ bias,
                                                float* __restrict__ Out, int N){
  __shared__ int   ssh[4][64];
  __shared__ float wsh[4][4][68];   // pad 64->68: heads land in distinct banks
  __shared__ int   chmax_sh;
  int wave = threadIdx.x >> 6, lane = threadIdx.x & 63;
  int n = blockIdx.x * 4 + wave;
  bool active = (n < N);
  int myhead = lane >> 4;
  int start = 0, deg = 0;
  float4 ed4 = make_float4(0.f, 0.f, 0.f, 0.f);
  if (active){
    start = rowptr[n];
    deg   = rowptr[n + 1] - start;
    ed4   = ((const float4*)ED)[n];
  }

  // pass A: per-head max over incoming edges (per-wave, no cross-wave sync)
  float4 m4 = make_float4(-3.0e38f, -3.0e38f, -3.0e38f, -3.0e38f);
  for (int i = lane; i < deg; i += 64){
    int s = ssrc[start + i];
    float4 e = ((const float4*)ES)[s];
    e.x += ed4.x; e.y += ed4.y; e.z += ed4.z; e.w += ed4.w;
    e.x = fmaxf(e.x, 0.2f * e.x); e.y = fmaxf(e.y, 0.2f * e.y);
    e.z = fmaxf(e.z, 0.2f * e.z); e.w = fmaxf(e.w, 0.2f * e.w);
    m4.x = fmaxf(m4.x, e.x); m4.y = fmaxf(m4.y, e.y);
    m4.z = fmaxf(m4.z, e.z); m4.w = fmaxf(m4.w, e.w);
  }
  #pragma unroll
  for (int off = 32; off > 0; off >>= 1){
    m4.x = fmaxf(m4.x, __shfl_xor(m4.x, off, 64));
    m4.y = fmaxf(m4.y, __shfl_xor(m4.y, off, 64));
    m4.z = fmaxf(m4.z, __shfl_xor(m4.z, off, 64));
    m4.w = fmaxf(m4.w, __shfl_xor(m4.w, off, 64));
  }

  // block-uniform chunk count
  int mych = (deg + 63) >> 6;          // >=1 for active nodes (self loop)
  if (threadIdx.x == 0) chmax_sh = 0;
  __syncthreads();
  if (lane == 0) atomicMax(&chmax_sh, mych);
  __syncthreads();
  int nch = chmax_sh;

  // pass B: weights + aggregate
  float4 acc = make_float4(0.f, 0.f, 0.f, 0.f);
  float4 den = make_float4(0.f, 0.f, 0.f, 0.f);
  for (int c = 0; c < nch; c++){
    int base = c << 6;
    int i = base + lane;
    float4 wt = make_float4(0.f, 0.f, 0.f, 0.f);
    int s = 0;
    if (active && i < deg){
      s = ssrc[start + i];
      float4 e = ((const float4*)ES)[s];
      e.x += ed4.x; e.y += ed4.y; e.z += ed4.z; e.w += ed4.w;
      e.x = fmaxf(e.x, 0.2f * e.x); e.y = fmaxf(e.y, 0.2f * e.y);
      e.z = fmaxf(e.z, 0.2f * e.z); e.w = fmaxf(e.w, 0.2f * e.w);
      wt.x = __expf(e.x - m4.x); wt.y = __expf(e.y - m4.y);
      wt.z = __expf(e.z - m4.z); wt.w = __expf(e.w - m4.w);
    }
    den.x += wt.x; den.y += wt.y; den.z += wt.z; den.w += wt.w;
    ssh[wave][lane] = s;
    wsh[wave][0][lane] = wt.x; wsh[wave][1][lane] = wt.y;
    wsh[wave][2][lane] = wt.z; wsh[wave][3][lane] = wt.w;
    __syncthreads();
    if (active && base < deg){
      int cl = min(deg - base, 64);
      const float* wrow = wsh[wave][myhead];
      int j = 0;
      for (; j + 3 < cl; j += 4){
        int s0 = ssh[wave][j], s1 = ssh[wave][j+1], s2 = ssh[wave][j+2], s3 = ssh[wave][j+3];
        float w0 = wrow[j], w1 = wrow[j+1], w2 = wrow[j+2], w3 = wrow[j+3];
        float4 r0 = ((const float4*)(Hh + (size_t)s0 * 256))[lane];
        float4 r1 = ((const float4*)(Hh + (size_t)s1 * 256))[lane];
        float4 r2 = ((const float4*)(Hh + (size_t)s2 * 256))[lane];
        float4 r3 = ((const float4*)(Hh + (size_t)s3 * 256))[lane];
        acc.x = fmaf(w0, r0.x, acc.x); acc.y = fmaf(w0, r0.y, acc.y);
        acc.z = fmaf(w0, r0.z, acc.z); acc.w = fmaf(w0, r0.w, acc.w);
        acc.x = fmaf(w1, r1.x, acc.x); acc.y = fmaf(w1, r1.y, acc.y);
        acc.z = fmaf(w1, r1.z, acc.z); acc.w = fmaf(w1, r1.w, acc.w);
        acc.x = fmaf(w2, r2.x, acc.x); acc.y = fmaf(w2, r2.y, acc.y);
        acc.z = fmaf(w2, r2.z, acc.z); acc.w = fmaf(w2, r2.w, acc.w);
        acc.x = fmaf(w3, r3.x, acc.x); acc.y = fmaf(w3, r3.y, acc.y);
        acc.z = fmaf(w3, r3.z, acc.z); acc.w = fmaf(w3, r3.w, acc.w);
      }
      for (; j < cl; ++j){
        int s0 = ssh[wave][j];
        float w0 = wrow[j];
        float4 r0 = ((const float4*)(Hh + (size_t)s0 * 256))[lane];
        acc.x = fmaf(w0, r0.x, acc.x); acc.y = fmaf(w0, r0.y, acc.y);
        acc.z = fmaf(w0, r0.z, acc.z); acc.w = fmaf(w0, r0.w, acc.w);
      }
    }
    __syncthreads();
  }

  if (!active) return;
  #pragma unroll
  for (int off = 32; off > 0; off >>= 1){
    den.x += __shfl_xor(den.x, off, 64);
    den.y += __shfl_xor(den.y, off, 64);
    den.z += __shfl_xor(den.z, off, 64);
    den.w += __shfl_xor(den.w, off, 64);
  }
  float d = (myhead == 0) ? den.x : (myhead == 1) ? den.y : (myhead == 2) ? den.z : den.w;
  float inv = 1.f / (d + 1e-16f);
  float4 b4 = ((const float4*)bias)[lane];
  float4 o;
  o.x = fmaxf(fmaf(acc.x, inv, b4.x), 0.f);
  o.y = fmaxf(fmaf(acc.y, inv, b4.y), 0.f);
  o.z = fmaxf(fmaf(acc.z, inv, b4.z), 0.f);
  o.w = fmaxf(fmaf(acc.w, inv, b4.w), 0.f);
  ((float4*)(Out + (size_t)n * 256))[lane] = o;
}

// ---------------- Layer 2 feature: h2 = x2 @ W2 (256->2), + scalar e ----------------
__global__ __launch_bounds__(256) void k_l2_feat(const float* __restrict__ X, const float* __restrict__ W,
                                                 const float* __restrict__ as_, const float* __restrict__ ad_,
                                                 float* __restrict__ H2, float* __restrict__ ES,
                                                 float* __restrict__ ED, int N){
  int wave = threadIdx.x >> 6, lane = threadIdx.x & 63;
  int n = blockIdx.x * 4 + wave;
  if (n >= N) return;
  const float* xr = X + (size_t)n * 256;
  float p0 = 0.f, p1 = 0.f;
  #pragma unroll
  for (int c = 0; c < 4; c++){
    int k = lane + 64*c;
    float xv = xr[k];
    p0 = fmaf(xv, W[2*k],     p0);
    p1 = fmaf(xv, W[2*k + 1], p1);
  }
  p0 = wred_sum(p0); p1 = wred_sum(p1);
  if (lane == 0){
    H2[n*2] = p0; H2[n*2 + 1] = p1;
    ES[n] = p0*as_[0] + p1*as_[1];
    ED[n] = p0*ad_[0] + p1*ad_[1];
  }
}

// ---------------- Edge phase layer 2: H=1, O=2, mean over heads == identity ----------------
__global__ __launch_bounds__(256) void k_edge2(const float* __restrict__ H2, const float* __restrict__ ES,
                                               const float* __restrict__ ED, const int* __restrict__ rowptr,
                                               const int* __restrict__ ssrc, const float* __restrict__ bias,
                                               float* __restrict__ Out, int N){
  int wave = threadIdx.x >> 6, lane = threadIdx.x & 63;
  int n = blockIdx.x * 4 + wave;
  if (n >= N) return;
  int start = rowptr[n], deg = rowptr[n + 1] - start;
  float ed = ED[n];
  float m = -3.0e38f;
  for (int i = lane; i < deg; i += 64){
    int s = ssrc[start + i];
    float a = ES[s] + ed; a = fmaxf(a, 0.2f * a);
    m = fmaxf(m, a);
  }
  m = wred_max(m);
  float den = 0.f, a0 = 0.f, a1 = 0.f;
  for (int i = lane; i < deg; i += 64){
    int s = ssrc[start + i];
    float a = ES[s] + ed; a = fmaxf(a, 0.2f * a);
    float w = __expf(a - m);
    den += w;
    a0 = fmaf(w, H2[s*2],     a0);
    a1 = fmaf(w, H2[s*2 + 1], a1);
  }
  den = wred_sum(den); a0 = wred_sum(a0); a1 = wred_sum(a1);
  if (lane == 0){
    float inv = 1.f / (den + 1e-16f);
    Out[n*2]     = fmaxf(a0 * inv + bias[0], 0.f);
    Out[n*2 + 1] = fmaxf(a1 * inv + bias[1], 0.f);
  }
}

extern "C" void kernel_launch(void* const* d_in, const int* in_sizes, int n_in,
                              void* d_out, int out_size, void* d_ws, size_t ws_size,
                              hipStream_t stream) {
  const float* x   = (const float*)d_in[0];
  const int*   ei  = (const int*)  d_in[1];
  const float* W0  = (const float*)d_in[2];
  const float* as0 = (const float*)d_in[3];
  const float* ad0 = (const float*)d_in[4];
  const float* b0  = (const float*)d_in[5];
  const float* W1  = (const float*)d_in[6];
  const float* as1 = (const float*)d_in[7];
  const float* ad1 = (const float*)d_in[8];
  const float* b1  = (const float*)d_in[9];
  const float* W2  = (const float*)d_in[10];
  const float* as2 = (const float*)d_in[11];
  const float* ad2 = (const float*)d_in[12];
  const float* b2  = (const float*)d_in[13];

  int N = in_sizes[0] / 2;
  int E = in_sizes[1] / 2;
  const int* src = ei;
  const int* dst = ei + E;

  char* ws = (char*)d_ws;
  size_t off = 0;
  auto alc = [&](size_t bytes){ size_t o = off; off += (bytes + 255) & ~(size_t)255; return o; };
  int*   deg    = (int*)  (ws + alc((size_t)N * 4));
  int*   rowptr = (int*)  (ws + alc((size_t)(N + 1) * 4));
  int*   cursor = (int*)  (ws + alc((size_t)N * 4));
  int*   ssrc   = (int*)  (ws + alc((size_t)(E + N) * 4));
  float* bufA   = (float*)(ws + alc((size_t)N * 256 * 4));
  float* bufB   = (float*)(ws + alc((size_t)N * 256 * 4));
  float* es0    = (float*)(ws + alc((size_t)N * 4 * 4));
  float* ed0    = (float*)(ws + alc((size_t)N * 4 * 4));
  float* es1    = (float*)(ws + alc((size_t)N * 4 * 4));
  float* ed1    = (float*)(ws + alc((size_t)N * 4 * 4));
  float* h2     = (float*)(ws + alc((size_t)N * 2 * 4));
  float* es2    = (float*)(ws + alc((size_t)N * 4));
  float* ed2    = (float*)(ws + alc((size_t)N * 4));
  float* out    = (float*)d_out;

  // CSR build (edge topology shared by all 3 layers)
  k_init_deg<<<(N + 255)/256, 256, 0, stream>>>(deg, N);
  k_hist    <<<(E + 255)/256, 256, 0, stream>>>(dst, E, deg);
  k_scan    <<<1, 1024, 0, stream>>>(deg, rowptr, N);
  k_selfloop<<<(N + 255)/256, 256, 0, stream>>>(rowptr, ssrc, cursor, N);
  k_scatter <<<(E + 255)/256, 256, 0, stream>>>(src, dst, E, cursor, ssrc);

  // Layer 0: 2 -> 4x64 concat, relu
  k_l0_feat<<<(N + 15)/16, 256, 0, stream>>>(x, W0, as0, ad0, bufA, es0, ed0, N);
  k_edge01 <<<(N + 3)/4, 256, 0, stream>>>(bufA, es0, ed0, rowptr, ssrc, b0, bufB, N);

  // Layer 1: 256 -> 4x64 concat, relu
  k_l1_feat<<<(N + 15)/16, 256, 0, stream>>>(bufB, W1, as1, ad1, bufA, es1, ed1, N);
  k_edge01 <<<(N + 3)/4, 256, 0, stream>>>(bufA, es1, ed1, rowptr, ssrc, b1, bufB, N);

  // Layer 2: 256 -> 2, mean over 1 head, relu
  k_l2_feat<<<(N + 3)/4, 256, 0, stream>>>(bufB, W2, as2, ad2, h2, es2, ed2, N);
  k_edge2  <<<(N + 3)/4, 256, 0, stream>>>(h2, es2, ed2, rowptr, ssrc, b2, out, N);
}

// Round 4
// 612.034 us; speedup vs baseline: 1.4534x; 1.1419x over previous
//
#include <hip/hip_runtime.h>
#include <math.h>

// 3-layer GAT, N=50000 nodes, E=800000 edges (+N self loops).
// Layers: (2 -> 4x64 concat) -> (256 -> 4x64 concat) -> (256 -> 1x2 mean), ReLU after each.
// Layer-1 GEMM (50000x256x256) runs on the matrix pipe via split-bf16 (hi+lo, 3 MFMAs).

typedef __attribute__((ext_vector_type(8))) short s16x8;
typedef __attribute__((ext_vector_type(4))) float f32x4;

__device__ __forceinline__ float wred_sum(float v){
  #pragma unroll
  for (int m = 32; m > 0; m >>= 1) v += __shfl_xor(v, m, 64);
  return v;
}
__device__ __forceinline__ float wred_max(float v){
  #pragma unroll
  for (int m = 32; m > 0; m >>= 1) v = fmaxf(v, __shfl_xor(v, m, 64));
  return v;
}
__device__ __forceinline__ unsigned short bf16_rne(float x){
  unsigned int u = __float_as_uint(x);
  unsigned int r = u + 0x7FFFu + ((u >> 16) & 1u);
  return (unsigned short)(r >> 16);
}

// ---------------- CSR build ----------------
__global__ __launch_bounds__(256) void k_init_deg(int* deg, int N){
  int i = blockIdx.x * 256 + threadIdx.x;
  if (i < N) deg[i] = 1;  // self loop
}

__global__ __launch_bounds__(256) void k_hist(const int* __restrict__ dst, int E, int* deg){
  int e = blockIdx.x * 256 + threadIdx.x;
  if (e < E) atomicAdd(&deg[dst[e]], 1);
}

__global__ __launch_bounds__(1024) void k_scan(const int* __restrict__ deg, int* rowptr, int N){
  __shared__ int sb[1024];
  int t = threadIdx.x;
  int chunk = (N + 1023) >> 10;
  int lo = t * chunk, hi = min(lo + chunk, N);
  int s = 0;
  for (int i = lo; i < hi; i++) s += deg[i];
  sb[t] = s;
  __syncthreads();
  for (int off = 1; off < 1024; off <<= 1){
    int v = (t >= off) ? sb[t - off] : 0;
    __syncthreads();
    sb[t] += v;
    __syncthreads();
  }
  int run = (t == 0) ? 0 : sb[t - 1];
  for (int i = lo; i < hi; i++){ rowptr[i] = run; run += deg[i]; }
  if (t == 1023) rowptr[N] = sb[1023];
}

__global__ __launch_bounds__(256) void k_selfloop(const int* __restrict__ rowptr, int* ssrc, int* cursor, int N){
  int i = blockIdx.x * 256 + threadIdx.x;
  if (i < N){ int p = rowptr[i]; ssrc[p] = i; cursor[i] = p + 1; }
}

__global__ __launch_bounds__(256) void k_scatter(const int* __restrict__ src, const int* __restrict__ dst,
                                                 int E, int* cursor, int* ssrc){
  int e = blockIdx.x * 256 + threadIdx.x;
  if (e < E){ int p = atomicAdd(&cursor[dst[e]], 1); ssrc[p] = src[e]; }
}

// ---------------- Layer 0 feature: h0 = x @ W0 (K=2), + e_src/e_dst ----------------
__global__ __launch_bounds__(256) void k_l0_feat(const float* __restrict__ X, const float* __restrict__ W,
                                                 const float* __restrict__ as_, const float* __restrict__ ad_,
                                                 float* __restrict__ Hh, float* __restrict__ ES,
                                                 float* __restrict__ ED, int N){
  int j = threadIdx.x;
  int n0 = blockIdx.x * 16;
  float w0 = W[j], w1 = W[256 + j];
  float asj = as_[j], adj = ad_[j];
  int head = j >> 6, lane = j & 63;
  #pragma unroll
  for (int i = 0; i < 16; i++){
    int n = n0 + i;
    if (n >= N) break;
    float x0 = X[2*n], x1 = X[2*n + 1];
    float hv = fmaf(x0, w0, x1 * w1);
    Hh[(size_t)n * 256 + j] = hv;
    float ps = wred_sum(hv * asj);
    float pd = wred_sum(hv * adj);
    if (lane == 0){ ES[n*4 + head] = ps; ED[n*4 + head] = pd; }
  }
}

// ---------------- W1 preconvert: W[k][j] f32 -> WhT/WlT [j][k] bf16 ----------------
__global__ __launch_bounds__(256) void k_w1conv(const float* __restrict__ W,
                                                unsigned short* __restrict__ WhT,
                                                unsigned short* __restrict__ WlT){
  int k = blockIdx.x, j = threadIdx.x;
  float w = W[k * 256 + j];
  unsigned short h = bf16_rne(w);
  float hf = __uint_as_float(((unsigned int)h) << 16);
  unsigned short l = bf16_rne(w - hf);
  WhT[j * 256 + k] = h;
  WlT[j * 256 + k] = l;
}

// ---------------- Layer 1 feature via split-bf16 MFMA ----------------
// C[50000,256] = X @ W1. Block: 64 rows, 4 waves x 16 rows, full 256 cols.
// K-steps of 32; LDS: Ah/Al [64][32], Bh/Bl [256][32] (40 KB).
__global__ __launch_bounds__(256) void k_l1_mfma(const float* __restrict__ X,
                                                 const unsigned short* __restrict__ WhT,
                                                 const unsigned short* __restrict__ WlT,
                                                 const float* __restrict__ as_, const float* __restrict__ ad_,
                                                 float* __restrict__ Hh, float* __restrict__ ES,
                                                 float* __restrict__ ED, int N){
  __shared__ unsigned short Ah[64 * 32], Al[64 * 32];
  __shared__ unsigned short Bh[256 * 32], Bl[256 * 32];
  int t = threadIdx.x;
  int wv = t >> 6, lane = t & 63;
  int lr = lane & 15, lg = lane >> 4;
  int rb = blockIdx.x * 64;

  f32x4 acc[16];
  #pragma unroll
  for (int c = 0; c < 16; c++) acc[c] = (f32x4){0.f, 0.f, 0.f, 0.f};

  // staging indices
  int arow = t >> 2, aseg = t & 3;           // A: row 0..63, 8-k segment 0..3
  int agrow = rb + arow;

  for (int ks = 0; ks < 8; ks++){
    int k0 = ks * 32;
    __syncthreads();
    // stage A: 64 rows x 32 k, f32 -> hi/lo bf16
    {
      float xv[8];
      if (agrow < N){
        const float4* p = (const float4*)(X + (size_t)agrow * 256 + k0 + aseg * 8);
        float4 v0 = p[0], v1 = p[1];
        xv[0]=v0.x; xv[1]=v0.y; xv[2]=v0.z; xv[3]=v0.w;
        xv[4]=v1.x; xv[5]=v1.y; xv[6]=v1.z; xv[7]=v1.w;
      } else {
        #pragma unroll
        for (int i = 0; i < 8; i++) xv[i] = 0.f;
      }
      union { unsigned short us[8]; uint4 v; } ph, pl;
      #pragma unroll
      for (int i = 0; i < 8; i++){
        unsigned short h = bf16_rne(xv[i]);
        float hf = __uint_as_float(((unsigned int)h) << 16);
        ph.us[i] = h;
        pl.us[i] = bf16_rne(xv[i] - hf);
      }
      *(uint4*)&Ah[arow * 32 + aseg * 8] = ph.v;
      *(uint4*)&Al[arow * 32 + aseg * 8] = pl.v;
    }
    // stage B: 256 cols x 32 k from preconverted WhT/WlT ([j][k] bf16)
    #pragma unroll
    for (int i = 0; i < 4; i++){
      int chunk = i * 256 + t;          // 1024 chunks of 16B
      int j = chunk >> 2, seg = chunk & 3;
      *(uint4*)&Bh[j * 32 + seg * 8] = *(const uint4*)&WhT[j * 256 + k0 + seg * 8];
      *(uint4*)&Bl[j * 32 + seg * 8] = *(const uint4*)&WlT[j * 256 + k0 + seg * 8];
    }
    __syncthreads();
    // compute
    s16x8 ah = *(const s16x8*)&Ah[(wv * 16 + lr) * 32 + lg * 8];
    s16x8 al = *(const s16x8*)&Al[(wv * 16 + lr) * 32 + lg * 8];
    #pragma unroll
    for (int c = 0; c < 16; c++){
      s16x8 bh = *(const s16x8*)&Bh[(c * 16 + lr) * 32 + lg * 8];
      s16x8 bl = *(const s16x8*)&Bl[(c * 16 + lr) * 32 + lg * 8];
      acc[c] = __builtin_amdgcn_mfma_f32_16x16x32_bf16(ah, bh, acc[c], 0, 0, 0);
      acc[c] = __builtin_amdgcn_mfma_f32_16x16x32_bf16(ah, bl, acc[c], 0, 0, 0);
      acc[c] = __builtin_amdgcn_mfma_f32_16x16x32_bf16(al, bh, acc[c], 0, 0, 0);
    }
  }

  // epilogue: write Hh, fused e_src/e_dst
  // C layout: row = rb + wv*16 + lg*4 + q, col = c*16 + lr
  #pragma unroll
  for (int q = 0; q < 4; q++){
    int n = rb + wv * 16 + lg * 4 + q;
    if (n < N){
      #pragma unroll
      for (int c = 0; c < 16; c++)
        Hh[(size_t)n * 256 + c * 16 + lr] = acc[c][q];
    }
  }
  float es_p[4][4], ed_p[4][4];   // [head][q]
  #pragma unroll
  for (int h = 0; h < 4; h++)
    #pragma unroll
    for (int q = 0; q < 4; q++){ es_p[h][q] = 0.f; ed_p[h][q] = 0.f; }
  #pragma unroll
  for (int c = 0; c < 16; c++){
    float asv = as_[c * 16 + lr];
    float adv = ad_[c * 16 + lr];
    int h = c >> 2;
    #pragma unroll
    for (int q = 0; q < 4; q++){
      es_p[h][q] = fmaf(acc[c][q], asv, es_p[h][q]);
      ed_p[h][q] = fmaf(acc[c][q], adv, ed_p[h][q]);
    }
  }
  #pragma unroll
  for (int h = 0; h < 4; h++)
    #pragma unroll
    for (int q = 0; q < 4; q++){
      #pragma unroll
      for (int mk = 1; mk < 16; mk <<= 1){
        es_p[h][q] += __shfl_xor(es_p[h][q], mk, 64);
        ed_p[h][q] += __shfl_xor(ed_p[h][q], mk, 64);
      }
    }
  if (lr == 0){
    #pragma unroll
    for (int q = 0; q < 4; q++){
      int n = rb + wv * 16 + lg * 4 + q;
      if (n < N){
        #pragma unroll
        for (int h = 0; h < 4; h++){
          ES[n * 4 + h] = es_p[h][q];
          ED[n * 4 + h] = ed_p[h][q];
        }
      }
    }
  }
}

// ---------------- Edge phase layers 0/1: one WAVE per dst node, all 4 heads ----------------
__global__ __launch_bounds__(256) void k_edge01(const float* __restrict__ Hh, const float* __restrict__ ES,
                                                const float* __restrict__ ED, const int* __restrict__ rowptr,
                                                const int* __restrict__ ssrc, const float* __restrict__ bias,
                                                float* __restrict__ Out, int N){
  __shared__ int   ssh[4][64];
  __shared__ float wsh[4][4][68];
  __shared__ int   chmax_sh;
  int wave = threadIdx.x >> 6, lane = threadIdx.x & 63;
  int n = blockIdx.x * 4 + wave;
  bool active = (n < N);
  int myhead = lane >> 4;
  int start = 0, deg = 0;
  float4 ed4 = make_float4(0.f, 0.f, 0.f, 0.f);
  if (active){
    start = rowptr[n];
    deg   = rowptr[n + 1] - start;
    ed4   = ((const float4*)ED)[n];
  }

  float4 m4 = make_float4(-3.0e38f, -3.0e38f, -3.0e38f, -3.0e38f);
  for (int i = lane; i < deg; i += 64){
    int s = ssrc[start + i];
    float4 e = ((const float4*)ES)[s];
    e.x += ed4.x; e.y += ed4.y; e.z += ed4.z; e.w += ed4.w;
    e.x = fmaxf(e.x, 0.2f * e.x); e.y = fmaxf(e.y, 0.2f * e.y);
    e.z = fmaxf(e.z, 0.2f * e.z); e.w = fmaxf(e.w, 0.2f * e.w);
    m4.x = fmaxf(m4.x, e.x); m4.y = fmaxf(m4.y, e.y);
    m4.z = fmaxf(m4.z, e.z); m4.w = fmaxf(m4.w, e.w);
  }
  #pragma unroll
  for (int off = 32; off > 0; off >>= 1){
    m4.x = fmaxf(m4.x, __shfl_xor(m4.x, off, 64));
    m4.y = fmaxf(m4.y, __shfl_xor(m4.y, off, 64));
    m4.z = fmaxf(m4.z, __shfl_xor(m4.z, off, 64));
    m4.w = fmaxf(m4.w, __shfl_xor(m4.w, off, 64));
  }

  int mych = (deg + 63) >> 6;
  if (threadIdx.x == 0) chmax_sh = 0;
  __syncthreads();
  if (lane == 0) atomicMax(&chmax_sh, mych);
  __syncthreads();
  int nch = chmax_sh;

  float4 acc = make_float4(0.f, 0.f, 0.f, 0.f);
  float4 den = make_float4(0.f, 0.f, 0.f, 0.f);
  for (int c = 0; c < nch; c++){
    int base = c << 6;
    int i = base + lane;
    float4 wt = make_float4(0.f, 0.f, 0.f, 0.f);
    int s = 0;
    if (active && i < deg){
      s = ssrc[start + i];
      float4 e = ((const float4*)ES)[s];
      e.x += ed4.x; e.y += ed4.y; e.z += ed4.z; e.w += ed4.w;
      e.x = fmaxf(e.x, 0.2f * e.x); e.y = fmaxf(e.y, 0.2f * e.y);
      e.z = fmaxf(e.z, 0.2f * e.z); e.w = fmaxf(e.w, 0.2f * e.w);
      wt.x = __expf(e.x - m4.x); wt.y = __expf(e.y - m4.y);
      wt.z = __expf(e.z - m4.z); wt.w = __expf(e.w - m4.w);
    }
    den.x += wt.x; den.y += wt.y; den.z += wt.z; den.w += wt.w;
    ssh[wave][lane] = s;
    wsh[wave][0][lane] = wt.x; wsh[wave][1][lane] = wt.y;
    wsh[wave][2][lane] = wt.z; wsh[wave][3][lane] = wt.w;
    __syncthreads();
    if (active && base < deg){
      int cl = min(deg - base, 64);
      const float* wrow = wsh[wave][myhead];
      int j = 0;
      for (; j + 3 < cl; j += 4){
        int s0 = ssh[wave][j], s1 = ssh[wave][j+1], s2 = ssh[wave][j+2], s3 = ssh[wave][j+3];
        float w0 = wrow[j], w1 = wrow[j+1], w2 = wrow[j+2], w3 = wrow[j+3];
        float4 r0 = ((const float4*)(Hh + (size_t)s0 * 256))[lane];
        float4 r1 = ((const float4*)(Hh + (size_t)s1 * 256))[lane];
        float4 r2 = ((const float4*)(Hh + (size_t)s2 * 256))[lane];
        float4 r3 = ((const float4*)(Hh + (size_t)s3 * 256))[lane];
        acc.x = fmaf(w0, r0.x, acc.x); acc.y = fmaf(w0, r0.y, acc.y);
        acc.z = fmaf(w0, r0.z, acc.z); acc.w = fmaf(w0, r0.w, acc.w);
        acc.x = fmaf(w1, r1.x, acc.x); acc.y = fmaf(w1, r1.y, acc.y);
        acc.z = fmaf(w1, r1.z, acc.z); acc.w = fmaf(w1, r1.w, acc.w);
        acc.x = fmaf(w2, r2.x, acc.x); acc.y = fmaf(w2, r2.y, acc.y);
        acc.z = fmaf(w2, r2.z, acc.z); acc.w = fmaf(w2, r2.w, acc.w);
        acc.x = fmaf(w3, r3.x, acc.x); acc.y = fmaf(w3, r3.y, acc.y);
        acc.z = fmaf(w3, r3.z, acc.z); acc.w = fmaf(w3, r3.w, acc.w);
      }
      for (; j < cl; ++j){
        int s0 = ssh[wave][j];
        float w0 = wrow[j];
        float4 r0 = ((const float4*)(Hh + (size_t)s0 * 256))[lane];
        acc.x = fmaf(w0, r0.x, acc.x); acc.y = fmaf(w0, r0.y, acc.y);
        acc.z = fmaf(w0, r0.z, acc.z); acc.w = fmaf(w0, r0.w, acc.w);
      }
    }
    __syncthreads();
  }

  if (!active) return;
  #pragma unroll
  for (int off = 32; off > 0; off >>= 1){
    den.x += __shfl_xor(den.x, off, 64);
    den.y += __shfl_xor(den.y, off, 64);
    den.z += __shfl_xor(den.z, off, 64);
    den.w += __shfl_xor(den.w, off, 64);
  }
  float d = (myhead == 0) ? den.x : (myhead == 1) ? den.y : (myhead == 2) ? den.z : den.w;
  float inv = 1.f / (d + 1e-16f);
  float4 b4 = ((const float4*)bias)[lane];
  float4 o;
  o.x = fmaxf(fmaf(acc.x, inv, b4.x), 0.f);
  o.y = fmaxf(fmaf(acc.y, inv, b4.y), 0.f);
  o.z = fmaxf(fmaf(acc.z, inv, b4.z), 0.f);
  o.w = fmaxf(fmaf(acc.w, inv, b4.w), 0.f);
  ((float4*)(Out + (size_t)n * 256))[lane] = o;
}

// ---------------- Layer 2 feature: h2 = x2 @ W2 (256->2), + scalar e ----------------
__global__ __launch_bounds__(256) void k_l2_feat(const float* __restrict__ X, const float* __restrict__ W,
                                                 const float* __restrict__ as_, const float* __restrict__ ad_,
                                                 float* __restrict__ H2, float* __restrict__ ES,
                                                 float* __restrict__ ED, int N){
  int wave = threadIdx.x >> 6, lane = threadIdx.x & 63;
  int n = blockIdx.x * 4 + wave;
  if (n >= N) return;
  const float* xr = X + (size_t)n * 256;
  float p0 = 0.f, p1 = 0.f;
  #pragma unroll
  for (int c = 0; c < 4; c++){
    int k = lane + 64*c;
    float xv = xr[k];
    p0 = fmaf(xv, W[2*k],     p0);
    p1 = fmaf(xv, W[2*k + 1], p1);
  }
  p0 = wred_sum(p0); p1 = wred_sum(p1);
  if (lane == 0){
    H2[n*2] = p0; H2[n*2 + 1] = p1;
    ES[n] = p0*as_[0] + p1*as_[1];
    ED[n] = p0*ad_[0] + p1*ad_[1];
  }
}

// ---------------- Edge phase layer 2: H=1, O=2 ----------------
__global__ __launch_bounds__(256) void k_edge2(const float* __restrict__ H2, const float* __restrict__ ES,
                                               const float* __restrict__ ED, const int* __restrict__ rowptr,
                                               const int* __restrict__ ssrc, const float* __restrict__ bias,
                                               float* __restrict__ Out, int N){
  int wave = threadIdx.x >> 6, lane = threadIdx.x & 63;
  int n = blockIdx.x * 4 + wave;
  if (n >= N) return;
  int start = rowptr[n], deg = rowptr[n + 1] - start;
  float ed = ED[n];
  float m = -3.0e38f;
  for (int i = lane; i < deg; i += 64){
    int s = ssrc[start + i];
    float a = ES[s] + ed; a = fmaxf(a, 0.2f * a);
    m = fmaxf(m, a);
  }
  m = wred_max(m);
  float den = 0.f, a0 = 0.f, a1 = 0.f;
  for (int i = lane; i < deg; i += 64){
    int s = ssrc[start + i];
    float a = ES[s] + ed; a = fmaxf(a, 0.2f * a);
    float w = __expf(a - m);
    den += w;
    a0 = fmaf(w, H2[s*2],     a0);
    a1 = fmaf(w, H2[s*2 + 1], a1);
  }
  den = wred_sum(den); a0 = wred_sum(a0); a1 = wred_sum(a1);
  if (lane == 0){
    float inv = 1.f / (den + 1e-16f);
    Out[n*2]     = fmaxf(a0 * inv + bias[0], 0.f);
    Out[n*2 + 1] = fmaxf(a1 * inv + bias[1], 0.f);
  }
}

extern "C" void kernel_launch(void* const* d_in, const int* in_sizes, int n_in,
                              void* d_out, int out_size, void* d_ws, size_t ws_size,
                              hipStream_t stream) {
  const float* x   = (const float*)d_in[0];
  const int*   ei  = (const int*)  d_in[1];
  const float* W0  = (const float*)d_in[2];
  const float* as0 = (const float*)d_in[3];
  const float* ad0 = (const float*)d_in[4];
  const float* b0  = (const float*)d_in[5];
  const float* W1  = (const float*)d_in[6];
  const float* as1 = (const float*)d_in[7];
  const float* ad1 = (const float*)d_in[8];
  const float* b1  = (const float*)d_in[9];
  const float* W2  = (const float*)d_in[10];
  const float* as2 = (const float*)d_in[11];
  const float* ad2 = (const float*)d_in[12];
  const float* b2  = (const float*)d_in[13];

  int N = in_sizes[0] / 2;
  int E = in_sizes[1] / 2;
  const int* src = ei;
  const int* dst = ei + E;

  char* ws = (char*)d_ws;
  size_t off = 0;
  auto alc = [&](size_t bytes){ size_t o = off; off += (bytes + 255) & ~(size_t)255; return o; };
  int*   deg    = (int*)  (ws + alc((size_t)N * 4));
  int*   rowptr = (int*)  (ws + alc((size_t)(N + 1) * 4));
  int*   cursor = (int*)  (ws + alc((size_t)N * 4));
  int*   ssrc   = (int*)  (ws + alc((size_t)(E + N) * 4));
  float* bufA   = (float*)(ws + alc((size_t)N * 256 * 4));
  float* bufB   = (float*)(ws + alc((size_t)N * 256 * 4));
  float* es0    = (float*)(ws + alc((size_t)N * 4 * 4));
  float* ed0    = (float*)(ws + alc((size_t)N * 4 * 4));
  float* es1    = (float*)(ws + alc((size_t)N * 4 * 4));
  float* ed1    = (float*)(ws + alc((size_t)N * 4 * 4));
  float* h2     = (float*)(ws + alc((size_t)N * 2 * 4));
  float* es2    = (float*)(ws + alc((size_t)N * 4));
  float* ed2    = (float*)(ws + alc((size_t)N * 4));
  unsigned short* wht = (unsigned short*)(ws + alc((size_t)256 * 256 * 2));
  unsigned short* wlt = (unsigned short*)(ws + alc((size_t)256 * 256 * 2));
  float* out    = (float*)d_out;

  // CSR build (edge topology shared by all 3 layers)
  k_init_deg<<<(N + 255)/256, 256, 0, stream>>>(deg, N);
  k_hist    <<<(E + 255)/256, 256, 0, stream>>>(dst, E, deg);
  k_scan    <<<1, 1024, 0, stream>>>(deg, rowptr, N);
  k_selfloop<<<(N + 255)/256, 256, 0, stream>>>(rowptr, ssrc, cursor, N);
  k_scatter <<<(E + 255)/256, 256, 0, stream>>>(src, dst, E, cursor, ssrc);
  k_w1conv  <<<256, 256, 0, stream>>>(W1, wht, wlt);

  // Layer 0: 2 -> 4x64 concat, relu
  k_l0_feat<<<(N + 15)/16, 256, 0, stream>>>(x, W0, as0, ad0, bufA, es0, ed0, N);
  k_edge01 <<<(N + 3)/4, 256, 0, stream>>>(bufA, es0, ed0, rowptr, ssrc, b0, bufB, N);

  // Layer 1: 256 -> 4x64 concat, relu (split-bf16 MFMA GEMM)
  k_l1_mfma<<<(N + 63)/64, 256, 0, stream>>>(bufB, wht, wlt, as1, ad1, bufA, es1, ed1, N);
  k_edge01 <<<(N + 3)/4, 256, 0, stream>>>(bufA, es1, ed1, rowptr, ssrc, b1, bufB, N);

  // Layer 2: 256 -> 2, mean over 1 head, relu
  k_l2_feat<<<(N + 3)/4, 256, 0, stream>>>(bufB, W2, as2, ad2, h2, es2, ed2, N);
  k_edge2  <<<(N + 3)/4, 256, 0, stream>>>(h2, es2, ed2, rowptr, ssrc, b2, out, N);
}

// Round 6
// 492.484 us; speedup vs baseline: 1.8062x; 1.2428x over previous
//
#include <hip/hip_runtime.h>
#include <math.h>

// 3-layer GAT, N=50000 nodes, E=800000 edges (+N self loops).
// Layer 0 collapsed to 2-dim aggregation (exact f32 algebra).
// Layer 1: h1 = x1@W1 via split-bf16 MFMA BEFORE aggregation (error-averaging),
// ES1/ED1 fused in GEMM epilogue. Layer-2 projection fused into edge1 epilogue.

typedef __attribute__((ext_vector_type(8))) short s16x8;
typedef __attribute__((ext_vector_type(4))) float f32x4;

__device__ __forceinline__ float wred_sum(float v){
  #pragma unroll
  for (int m = 32; m > 0; m >>= 1) v += __shfl_xor(v, m, 64);
  return v;
}
__device__ __forceinline__ void wred_sum4(float4& v){
  #pragma unroll
  for (int m = 32; m > 0; m >>= 1){
    v.x += __shfl_xor(v.x, m, 64);
    v.y += __shfl_xor(v.y, m, 64);
    v.z += __shfl_xor(v.z, m, 64);
    v.w += __shfl_xor(v.w, m, 64);
  }
}
__device__ __forceinline__ void wred_max4(float4& v){
  #pragma unroll
  for (int m = 32; m > 0; m >>= 1){
    v.x = fmaxf(v.x, __shfl_xor(v.x, m, 64));
    v.y = fmaxf(v.y, __shfl_xor(v.y, m, 64));
    v.z = fmaxf(v.z, __shfl_xor(v.z, m, 64));
    v.w = fmaxf(v.w, __shfl_xor(v.w, m, 64));
  }
}
__device__ __forceinline__ unsigned short bf16_rne(float x){
  unsigned int u = __float_as_uint(x);
  unsigned int r = u + 0x7FFFu + ((u >> 16) & 1u);
  return (unsigned short)(r >> 16);
}

// ---------------- CSR build ----------------
__global__ __launch_bounds__(256) void k_init_deg(int* deg, int N){
  int i = blockIdx.x * 256 + threadIdx.x;
  if (i < N) deg[i] = 1;  // self loop
}
__global__ __launch_bounds__(256) void k_hist(const int* __restrict__ dst, int E, int* deg){
  int e = blockIdx.x * 256 + threadIdx.x;
  if (e < E) atomicAdd(&deg[dst[e]], 1);
}
__global__ __launch_bounds__(1024) void k_scan(const int* __restrict__ deg, int* rowptr, int N){
  __shared__ int sb[1024];
  int t = threadIdx.x;
  int chunk = (N + 1023) >> 10;
  int lo = t * chunk, hi = min(lo + chunk, N);
  int s = 0;
  for (int i = lo; i < hi; i++) s += deg[i];
  sb[t] = s;
  __syncthreads();
  for (int off = 1; off < 1024; off <<= 1){
    int v = (t >= off) ? sb[t - off] : 0;
    __syncthreads();
    sb[t] += v;
    __syncthreads();
  }
  int run = (t == 0) ? 0 : sb[t - 1];
  for (int i = lo; i < hi; i++){ rowptr[i] = run; run += deg[i]; }
  if (t == 1023) rowptr[N] = sb[1023];
}
__global__ __launch_bounds__(256) void k_selfloop(const int* __restrict__ rowptr, int* ssrc, int* cursor, int N){
  int i = blockIdx.x * 256 + threadIdx.x;
  if (i < N){ int p = rowptr[i]; ssrc[p] = i; cursor[i] = p + 1; }
}
__global__ __launch_bounds__(256) void k_scatter(const int* __restrict__ src, const int* __restrict__ dst,
                                                 int E, int* cursor, int* ssrc){
  int e = blockIdx.x * 256 + threadIdx.x;
  if (e < E){ int p = atomicAdd(&cursor[dst[e]], 1); ssrc[p] = src[e]; }
}

// ---------------- W1 preconvert: W[k][j] f32 -> WhT/WlT [j][k] bf16 ----------------
__global__ __launch_bounds__(256) void k_w1conv(const float* __restrict__ W,
                                                unsigned short* __restrict__ WhT,
                                                unsigned short* __restrict__ WlT){
  int k = blockIdx.x, j = threadIdx.x;
  float w = W[k * 256 + j];
  unsigned short h = bf16_rne(w);
  float hf = __uint_as_float(((unsigned int)h) << 16);
  unsigned short l = bf16_rne(w - hf);
  WhT[j * 256 + k] = h;
  WlT[j * 256 + k] = l;
}

// ---------------- prep: vs = W0 @ a_{src,dst}0 (2x4 each) ----------------
__global__ __launch_bounds__(64) void k_prep_vs(const float* __restrict__ W0, const float* __restrict__ as0,
                                                const float* __restrict__ ad0, float* __restrict__ vs){
  int t = threadIdx.x;
  if (t < 8){
    int j = t >> 2, h = t & 3;
    float ss = 0.f, dd = 0.f;
    #pragma unroll 8
    for (int o = 0; o < 64; o++){
      float w = W0[j * 256 + h * 64 + o];
      ss = fmaf(w, as0[h * 64 + o], ss);
      dd = fmaf(w, ad0[h * 64 + o], dd);
    }
    vs[j * 4 + h]     = ss;   // src proj
    vs[8 + j * 4 + h] = dd;   // dst proj
  }
}

// ---------------- ES0/ED0[n,h] = x[n,0]*vs[0,h] + x[n,1]*vs[1,h] ----------------
__global__ __launch_bounds__(256) void k_es0(const float* __restrict__ X, const float* __restrict__ vs,
                                             float* __restrict__ ES0, float* __restrict__ ED0, int N){
  int i = blockIdx.x * 256 + threadIdx.x;
  if (i >= N) return;
  float x0 = X[2 * i], x1 = X[2 * i + 1];
  float4 va = ((const float4*)vs)[0], vb = ((const float4*)vs)[1];
  float4 vc = ((const float4*)vs)[2], vd = ((const float4*)vs)[3];
  float4 es, ed;
  es.x = fmaf(x0, va.x, x1 * vb.x); es.y = fmaf(x0, va.y, x1 * vb.y);
  es.z = fmaf(x0, va.z, x1 * vb.z); es.w = fmaf(x0, va.w, x1 * vb.w);
  ed.x = fmaf(x0, vc.x, x1 * vd.x); ed.y = fmaf(x0, vc.y, x1 * vd.y);
  ed.z = fmaf(x0, vc.z, x1 * vd.z); ed.w = fmaf(x0, vc.w, x1 * vd.w);
  ((float4*)ES0)[i] = es;
  ((float4*)ED0)[i] = ed;
}

// ---------------- edge0: segment softmax over 4 heads, aggregate 2-dim x -> agg2[N][4][2] ----------------
__global__ __launch_bounds__(256) void k_edge0(const float* __restrict__ X, const float* __restrict__ ES0,
                                               const float* __restrict__ ED0, const int* __restrict__ rowptr,
                                               const int* __restrict__ ssrc, float* __restrict__ agg2, int N){
  int wave = threadIdx.x >> 6, lane = threadIdx.x & 63;
  int n = blockIdx.x * 4 + wave;
  if (n >= N) return;
  int start = rowptr[n], deg = rowptr[n + 1] - start;
  float4 ed4 = ((const float4*)ED0)[n];
  float4 m4 = make_float4(-3.0e38f, -3.0e38f, -3.0e38f, -3.0e38f);
  for (int i = lane; i < deg; i += 64){
    int s = ssrc[start + i];
    float4 e = ((const float4*)ES0)[s];
    e.x += ed4.x; e.y += ed4.y; e.z += ed4.z; e.w += ed4.w;
    e.x = fmaxf(e.x, 0.2f * e.x); e.y = fmaxf(e.y, 0.2f * e.y);
    e.z = fmaxf(e.z, 0.2f * e.z); e.w = fmaxf(e.w, 0.2f * e.w);
    m4.x = fmaxf(m4.x, e.x); m4.y = fmaxf(m4.y, e.y);
    m4.z = fmaxf(m4.z, e.z); m4.w = fmaxf(m4.w, e.w);
  }
  wred_max4(m4);
  float4 den = make_float4(0.f,0.f,0.f,0.f);
  float4 a0  = make_float4(0.f,0.f,0.f,0.f);
  float4 a1  = make_float4(0.f,0.f,0.f,0.f);
  for (int i = lane; i < deg; i += 64){
    int s = ssrc[start + i];
    float4 e = ((const float4*)ES0)[s];
    e.x += ed4.x; e.y += ed4.y; e.z += ed4.z; e.w += ed4.w;
    e.x = fmaxf(e.x, 0.2f * e.x); e.y = fmaxf(e.y, 0.2f * e.y);
    e.z = fmaxf(e.z, 0.2f * e.z); e.w = fmaxf(e.w, 0.2f * e.w);
    float4 wt;
    wt.x = __expf(e.x - m4.x); wt.y = __expf(e.y - m4.y);
    wt.z = __expf(e.z - m4.z); wt.w = __expf(e.w - m4.w);
    den.x += wt.x; den.y += wt.y; den.z += wt.z; den.w += wt.w;
    float2 xv = ((const float2*)X)[s];
    a0.x = fmaf(wt.x, xv.x, a0.x); a0.y = fmaf(wt.y, xv.x, a0.y);
    a0.z = fmaf(wt.z, xv.x, a0.z); a0.w = fmaf(wt.w, xv.x, a0.w);
    a1.x = fmaf(wt.x, xv.y, a1.x); a1.y = fmaf(wt.y, xv.y, a1.y);
    a1.z = fmaf(wt.z, xv.y, a1.z); a1.w = fmaf(wt.w, xv.y, a1.w);
  }
  wred_sum4(den); wred_sum4(a0); wred_sum4(a1);
  if (lane == 0){
    float4 inv;
    inv.x = 1.f / (den.x + 1e-16f); inv.y = 1.f / (den.y + 1e-16f);
    inv.z = 1.f / (den.z + 1e-16f); inv.w = 1.f / (den.w + 1e-16f);
    float* g = agg2 + (size_t)n * 8;
    g[0] = a0.x * inv.x; g[1] = a1.x * inv.x;
    g[2] = a0.y * inv.y; g[3] = a1.y * inv.y;
    g[4] = a0.z * inv.z; g[5] = a1.z * inv.z;
    g[6] = a0.w * inv.w; g[7] = a1.w * inv.w;
  }
}

// ---------------- mid: x1 = relu(agg2 @ W0 + b0) ----------------
__global__ __launch_bounds__(256) void k_mid2(const float* __restrict__ agg2, const float* __restrict__ W0,
                                              const float* __restrict__ b0, float* __restrict__ X1, int N){
  int wave = threadIdx.x >> 6, lane = threadIdx.x & 63;
  int n = blockIdx.x * 4 + wave;
  if (n >= N) return;
  int hh = lane >> 4;
  float a0 = agg2[(size_t)n * 8 + hh * 2];
  float a1 = agg2[(size_t)n * 8 + hh * 2 + 1];
  float4 w0r = ((const float4*)W0)[lane];
  float4 w1r = ((const float4*)(W0 + 256))[lane];
  float4 bb  = ((const float4*)b0)[lane];
  float4 v;
  v.x = fmaxf(fmaf(a0, w0r.x, fmaf(a1, w1r.x, bb.x)), 0.f);
  v.y = fmaxf(fmaf(a0, w0r.y, fmaf(a1, w1r.y, bb.y)), 0.f);
  v.z = fmaxf(fmaf(a0, w0r.z, fmaf(a1, w1r.z, bb.z)), 0.f);
  v.w = fmaxf(fmaf(a0, w0r.w, fmaf(a1, w1r.w, bb.w)), 0.f);
  ((float4*)(X1 + (size_t)n * 256))[lane] = v;
}

// ---------------- Layer 1 GEMM: h1 = x1 @ W1 (split-bf16 MFMA) + ES1/ED1 epilogue ----------------
__global__ __launch_bounds__(256) void k_l1_mfma(const float* __restrict__ X,
                                                 const unsigned short* __restrict__ WhT,
                                                 const unsigned short* __restrict__ WlT,
                                                 const float* __restrict__ as_, const float* __restrict__ ad_,
                                                 float* __restrict__ Hh, float* __restrict__ ES,
                                                 float* __restrict__ ED, int N){
  __shared__ unsigned short Ah[64 * 32], Al[64 * 32];
  __shared__ unsigned short Bh[256 * 32], Bl[256 * 32];
  int t = threadIdx.x;
  int wv = t >> 6, lane = t & 63;
  int lr = lane & 15, lg = lane >> 4;
  int rb = blockIdx.x * 64;

  f32x4 acc[16];
  #pragma unroll
  for (int c = 0; c < 16; c++) acc[c] = (f32x4){0.f, 0.f, 0.f, 0.f};

  int arow = t >> 2, aseg = t & 3;
  int agrow = rb + arow;

  for (int ks = 0; ks < 8; ks++){
    int k0 = ks * 32;
    __syncthreads();
    {
      float xv[8];
      if (agrow < N){
        const float4* p = (const float4*)(X + (size_t)agrow * 256 + k0 + aseg * 8);
        float4 v0 = p[0], v1 = p[1];
        xv[0]=v0.x; xv[1]=v0.y; xv[2]=v0.z; xv[3]=v0.w;
        xv[4]=v1.x; xv[5]=v1.y; xv[6]=v1.z; xv[7]=v1.w;
      } else {
        #pragma unroll
        for (int i = 0; i < 8; i++) xv[i] = 0.f;
      }
      union { unsigned short us[8]; uint4 v; } ph, pl;
      #pragma unroll
      for (int i = 0; i < 8; i++){
        unsigned short h = bf16_rne(xv[i]);
        float hf = __uint_as_float(((unsigned int)h) << 16);
        ph.us[i] = h;
        pl.us[i] = bf16_rne(xv[i] - hf);
      }
      *(uint4*)&Ah[arow * 32 + aseg * 8] = ph.v;
      *(uint4*)&Al[arow * 32 + aseg * 8] = pl.v;
    }
    #pragma unroll
    for (int i = 0; i < 4; i++){
      int chunk = i * 256 + t;
      int j = chunk >> 2, seg = chunk & 3;
      *(uint4*)&Bh[j * 32 + seg * 8] = *(const uint4*)&WhT[j * 256 + k0 + seg * 8];
      *(uint4*)&Bl[j * 32 + seg * 8] = *(const uint4*)&WlT[j * 256 + k0 + seg * 8];
    }
    __syncthreads();
    s16x8 ah = *(const s16x8*)&Ah[(wv * 16 + lr) * 32 + lg * 8];
    s16x8 al = *(const s16x8*)&Al[(wv * 16 + lr) * 32 + lg * 8];
    #pragma unroll
    for (int c = 0; c < 16; c++){
      s16x8 bh = *(const s16x8*)&Bh[(c * 16 + lr) * 32 + lg * 8];
      s16x8 bl = *(const s16x8*)&Bl[(c * 16 + lr) * 32 + lg * 8];
      acc[c] = __builtin_amdgcn_mfma_f32_16x16x32_bf16(ah, bh, acc[c], 0, 0, 0);
      acc[c] = __builtin_amdgcn_mfma_f32_16x16x32_bf16(ah, bl, acc[c], 0, 0, 0);
      acc[c] = __builtin_amdgcn_mfma_f32_16x16x32_bf16(al, bh, acc[c], 0, 0, 0);
    }
  }

  // epilogue: write Hh, fused e_src/e_dst (row = rb + wv*16 + lg*4 + q, col = c*16 + lr)
  #pragma unroll
  for (int q = 0; q < 4; q++){
    int n = rb + wv * 16 + lg * 4 + q;
    if (n < N){
      #pragma unroll
      for (int c = 0; c < 16; c++)
        Hh[(size_t)n * 256 + c * 16 + lr] = acc[c][q];
    }
  }
  float es_p[4][4], ed_p[4][4];
  #pragma unroll
  for (int h = 0; h < 4; h++)
    #pragma unroll
    for (int q = 0; q < 4; q++){ es_p[h][q] = 0.f; ed_p[h][q] = 0.f; }
  #pragma unroll
  for (int c = 0; c < 16; c++){
    float asv = as_[c * 16 + lr];
    float adv = ad_[c * 16 + lr];
    int h = c >> 2;
    #pragma unroll
    for (int q = 0; q < 4; q++){
      es_p[h][q] = fmaf(acc[c][q], asv, es_p[h][q]);
      ed_p[h][q] = fmaf(acc[c][q], adv, ed_p[h][q]);
    }
  }
  #pragma unroll
  for (int h = 0; h < 4; h++)
    #pragma unroll
    for (int q = 0; q < 4; q++){
      #pragma unroll
      for (int mk = 1; mk < 16; mk <<= 1){
        es_p[h][q] += __shfl_xor(es_p[h][q], mk, 64);
        ed_p[h][q] += __shfl_xor(ed_p[h][q], mk, 64);
      }
    }
  if (lr == 0){
    #pragma unroll
    for (int q = 0; q < 4; q++){
      int n = rb + wv * 16 + lg * 4 + q;
      if (n < N){
        #pragma unroll
        for (int h = 0; h < 4; h++){
          ES[n * 4 + h] = es_p[h][q];
          ED[n * 4 + h] = ed_p[h][q];
        }
      }
    }
  }
}

// ---------------- aggregate helper ----------------
__device__ __forceinline__ void agg_rows(const float* __restrict__ Hh, const int* ssh, const float* wrow,
                                         int cl, int lane, float4& acc){
  int j = 0;
  for (; j + 7 < cl; j += 8){
    int s0=ssh[j],s1=ssh[j+1],s2=ssh[j+2],s3=ssh[j+3];
    int s4=ssh[j+4],s5=ssh[j+5],s6=ssh[j+6],s7=ssh[j+7];
    float w0=wrow[j],w1=wrow[j+1],w2=wrow[j+2],w3=wrow[j+3];
    float w4=wrow[j+4],w5=wrow[j+5],w6=wrow[j+6],w7=wrow[j+7];
    float4 r0 = ((const float4*)(Hh + (size_t)s0 * 256))[lane];
    float4 r1 = ((const float4*)(Hh + (size_t)s1 * 256))[lane];
    float4 r2 = ((const float4*)(Hh + (size_t)s2 * 256))[lane];
    float4 r3 = ((const float4*)(Hh + (size_t)s3 * 256))[lane];
    float4 r4 = ((const float4*)(Hh + (size_t)s4 * 256))[lane];
    float4 r5 = ((const float4*)(Hh + (size_t)s5 * 256))[lane];
    float4 r6 = ((const float4*)(Hh + (size_t)s6 * 256))[lane];
    float4 r7 = ((const float4*)(Hh + (size_t)s7 * 256))[lane];
    acc.x=fmaf(w0,r0.x,acc.x); acc.y=fmaf(w0,r0.y,acc.y); acc.z=fmaf(w0,r0.z,acc.z); acc.w=fmaf(w0,r0.w,acc.w);
    acc.x=fmaf(w1,r1.x,acc.x); acc.y=fmaf(w1,r1.y,acc.y); acc.z=fmaf(w1,r1.z,acc.z); acc.w=fmaf(w1,r1.w,acc.w);
    acc.x=fmaf(w2,r2.x,acc.x); acc.y=fmaf(w2,r2.y,acc.y); acc.z=fmaf(w2,r2.z,acc.z); acc.w=fmaf(w2,r2.w,acc.w);
    acc.x=fmaf(w3,r3.x,acc.x); acc.y=fmaf(w3,r3.y,acc.y); acc.z=fmaf(w3,r3.z,acc.z); acc.w=fmaf(w3,r3.w,acc.w);
    acc.x=fmaf(w4,r4.x,acc.x); acc.y=fmaf(w4,r4.y,acc.y); acc.z=fmaf(w4,r4.z,acc.z); acc.w=fmaf(w4,r4.w,acc.w);
    acc.x=fmaf(w5,r5.x,acc.x); acc.y=fmaf(w5,r5.y,acc.y); acc.z=fmaf(w5,r5.z,acc.z); acc.w=fmaf(w5,r5.w,acc.w);
    acc.x=fmaf(w6,r6.x,acc.x); acc.y=fmaf(w6,r6.y,acc.y); acc.z=fmaf(w6,r6.z,acc.z); acc.w=fmaf(w6,r6.w,acc.w);
    acc.x=fmaf(w7,r7.x,acc.x); acc.y=fmaf(w7,r7.y,acc.y); acc.z=fmaf(w7,r7.z,acc.z); acc.w=fmaf(w7,r7.w,acc.w);
  }
  for (; j + 3 < cl; j += 4){
    int s0=ssh[j],s1=ssh[j+1],s2=ssh[j+2],s3=ssh[j+3];
    float w0=wrow[j],w1=wrow[j+1],w2=wrow[j+2],w3=wrow[j+3];
    float4 r0 = ((const float4*)(Hh + (size_t)s0 * 256))[lane];
    float4 r1 = ((const float4*)(Hh + (size_t)s1 * 256))[lane];
    float4 r2 = ((const float4*)(Hh + (size_t)s2 * 256))[lane];
    float4 r3 = ((const float4*)(Hh + (size_t)s3 * 256))[lane];
    acc.x=fmaf(w0,r0.x,acc.x); acc.y=fmaf(w0,r0.y,acc.y); acc.z=fmaf(w0,r0.z,acc.z); acc.w=fmaf(w0,r0.w,acc.w);
    acc.x=fmaf(w1,r1.x,acc.x); acc.y=fmaf(w1,r1.y,acc.y); acc.z=fmaf(w1,r1.z,acc.z); acc.w=fmaf(w1,r1.w,acc.w);
    acc.x=fmaf(w2,r2.x,acc.x); acc.y=fmaf(w2,r2.y,acc.y); acc.z=fmaf(w2,r2.z,acc.z); acc.w=fmaf(w2,r2.w,acc.w);
    acc.x=fmaf(w3,r3.x,acc.x); acc.y=fmaf(w3,r3.y,acc.y); acc.z=fmaf(w3,r3.z,acc.z); acc.w=fmaf(w3,r3.w,acc.w);
  }
  for (; j < cl; ++j){
    int s0 = ssh[j];
    float w0 = wrow[j];
    float4 r0 = ((const float4*)(Hh + (size_t)s0 * 256))[lane];
    acc.x=fmaf(w0,r0.x,acc.x); acc.y=fmaf(w0,r0.y,acc.y); acc.z=fmaf(w0,r0.z,acc.z); acc.w=fmaf(w0,r0.w,acc.w);
  }
}

// ---------------- edge1: one WAVE per dst, all 4 heads; epilogue fuses b1+relu+W2 proj -> h2, ES2, ED2 ----------------
__global__ __launch_bounds__(256) void k_edge1(const float* __restrict__ Hh, const float* __restrict__ ES,
                                               const float* __restrict__ ED, const int* __restrict__ rowptr,
                                               const int* __restrict__ ssrc, const float* __restrict__ b1,
                                               const float* __restrict__ W2,
                                               const float* __restrict__ as2, const float* __restrict__ ad2,
                                               float* __restrict__ H2, float* __restrict__ ES2,
                                               float* __restrict__ ED2, int N){
  __shared__ int   ssh[4][64];
  __shared__ float wsh[4][4][68];
  __shared__ int   chmax_sh;
  int wave = threadIdx.x >> 6, lane = threadIdx.x & 63;
  int n = blockIdx.x * 4 + wave;
  bool active = (n < N);
  int myhead = lane >> 4;
  int start = 0, deg = 0;
  float4 ed4 = make_float4(0.f,0.f,0.f,0.f);
  if (active){
    start = rowptr[n];
    deg   = rowptr[n + 1] - start;
    ed4   = ((const float4*)ED)[n];
  }

  // pass A: per-head max; remember this lane's edge (valid when deg<=64)
  float4 m4 = make_float4(-3.0e38f,-3.0e38f,-3.0e38f,-3.0e38f);
  int    s_keep = 0;
  float4 a_keep = make_float4(0.f,0.f,0.f,0.f);
  for (int i = lane; i < deg; i += 64){
    int s = ssrc[start + i];
    float4 e = ((const float4*)ES)[s];
    e.x += ed4.x; e.y += ed4.y; e.z += ed4.z; e.w += ed4.w;
    e.x = fmaxf(e.x, 0.2f * e.x); e.y = fmaxf(e.y, 0.2f * e.y);
    e.z = fmaxf(e.z, 0.2f * e.z); e.w = fmaxf(e.w, 0.2f * e.w);
    s_keep = s; a_keep = e;
    m4.x = fmaxf(m4.x, e.x); m4.y = fmaxf(m4.y, e.y);
    m4.z = fmaxf(m4.z, e.z); m4.w = fmaxf(m4.w, e.w);
  }
  wred_max4(m4);

  int mych = active ? ((deg + 63) >> 6) : 0;
  if (threadIdx.x == 0) chmax_sh = 0;
  __syncthreads();
  if (lane == 0) atomicMax(&chmax_sh, mych);
  __syncthreads();
  int nch = chmax_sh;

  float4 acc = make_float4(0.f,0.f,0.f,0.f);
  float4 den = make_float4(0.f,0.f,0.f,0.f);

  if (nch == 1){
    float4 wt = make_float4(0.f,0.f,0.f,0.f);
    if (active && lane < deg){
      wt.x = __expf(a_keep.x - m4.x); wt.y = __expf(a_keep.y - m4.y);
      wt.z = __expf(a_keep.z - m4.z); wt.w = __expf(a_keep.w - m4.w);
    }
    den = wt;
    ssh[wave][lane] = s_keep;
    wsh[wave][0][lane] = wt.x; wsh[wave][1][lane] = wt.y;
    wsh[wave][2][lane] = wt.z; wsh[wave][3][lane] = wt.w;
    __syncthreads();
    if (active)
      agg_rows(Hh, ssh[wave], wsh[wave][myhead], deg, lane, acc);
    __syncthreads();
  } else {
    for (int c = 0; c < nch; c++){
      int base = c << 6;
      int i = base + lane;
      float4 wt = make_float4(0.f,0.f,0.f,0.f);
      int s = 0;
      if (active && i < deg){
        s = ssrc[start + i];
        float4 e = ((const float4*)ES)[s];
        e.x += ed4.x; e.y += ed4.y; e.z += ed4.z; e.w += ed4.w;
        e.x = fmaxf(e.x, 0.2f * e.x); e.y = fmaxf(e.y, 0.2f * e.y);
        e.z = fmaxf(e.z, 0.2f * e.z); e.w = fmaxf(e.w, 0.2f * e.w);
        wt.x = __expf(e.x - m4.x); wt.y = __expf(e.y - m4.y);
        wt.z = __expf(e.z - m4.z); wt.w = __expf(e.w - m4.w);
      }
      den.x += wt.x; den.y += wt.y; den.z += wt.z; den.w += wt.w;
      ssh[wave][lane] = s;
      wsh[wave][0][lane] = wt.x; wsh[wave][1][lane] = wt.y;
      wsh[wave][2][lane] = wt.z; wsh[wave][3][lane] = wt.w;
      __syncthreads();
      if (active && base < deg)
        agg_rows(Hh, ssh[wave], wsh[wave][myhead], min(deg - base, 64), lane, acc);
      __syncthreads();
    }
  }

  if (!active) return;
  wred_sum4(den);
  float d = (myhead == 0) ? den.x : (myhead == 1) ? den.y : (myhead == 2) ? den.z : den.w;
  float inv = 1.f / (d + 1e-16f);
  float4 bb = ((const float4*)b1)[lane];
  float4 v;
  v.x = fmaxf(fmaf(acc.x, inv, bb.x), 0.f);
  v.y = fmaxf(fmaf(acc.y, inv, bb.y), 0.f);
  v.z = fmaxf(fmaf(acc.z, inv, bb.z), 0.f);
  v.w = fmaxf(fmaf(acc.w, inv, bb.w), 0.f);
  // W2 proj: lane's cols 4l..4l+3; W2 is [256][2]
  float4 wA = ((const float4*)W2)[2*lane];      // cols 4l,4l+1: (w0a,w0b,w1a,w1b)
  float4 wB = ((const float4*)W2)[2*lane + 1];  // cols 4l+2,4l+3
  float p0 = v.x*wA.x + v.y*wA.z + v.z*wB.x + v.w*wB.z;
  float p1 = v.x*wA.y + v.y*wA.w + v.z*wB.y + v.w*wB.w;
  p0 = wred_sum(p0); p1 = wred_sum(p1);
  if (lane == 0){
    H2[n*2]     = p0;
    H2[n*2 + 1] = p1;
    ES2[n] = p0*as2[0] + p1*as2[1];
    ED2[n] = p0*ad2[0] + p1*ad2[1];
  }
}

// ---------------- edge2: H=1, O=2, + b2, relu ----------------
__global__ __launch_bounds__(256) void k_edge2(const float* __restrict__ H2, const float* __restrict__ ES,
                                               const float* __restrict__ ED, const int* __restrict__ rowptr,
                                               const int* __restrict__ ssrc, const float* __restrict__ bias,
                                               float* __restrict__ Out, int N){
  int wave = threadIdx.x >> 6, lane = threadIdx.x & 63;
  int n = blockIdx.x * 4 + wave;
  if (n >= N) return;
  int start = rowptr[n], deg = rowptr[n + 1] - start;
  float ed = ED[n];
  float m = -3.0e38f;
  for (int i = lane; i < deg; i += 64){
    int s = ssrc[start + i];
    float a = ES[s] + ed; a = fmaxf(a, 0.2f * a);
    m = fmaxf(m, a);
  }
  #pragma unroll
  for (int mk = 32; mk > 0; mk >>= 1) m = fmaxf(m, __shfl_xor(m, mk, 64));
  float den = 0.f, a0 = 0.f, a1 = 0.f;
  for (int i = lane; i < deg; i += 64){
    int s = ssrc[start + i];
    float a = ES[s] + ed; a = fmaxf(a, 0.2f * a);
    float w = __expf(a - m);
    den += w;
    a0 = fmaf(w, H2[s*2],     a0);
    a1 = fmaf(w, H2[s*2 + 1], a1);
  }
  den = wred_sum(den); a0 = wred_sum(a0); a1 = wred_sum(a1);
  if (lane == 0){
    float inv = 1.f / (den + 1e-16f);
    Out[n*2]     = fmaxf(a0 * inv + bias[0], 0.f);
    Out[n*2 + 1] = fmaxf(a1 * inv + bias[1], 0.f);
  }
}

extern "C" void kernel_launch(void* const* d_in, const int* in_sizes, int n_in,
                              void* d_out, int out_size, void* d_ws, size_t ws_size,
                              hipStream_t stream) {
  const float* x   = (const float*)d_in[0];
  const int*   ei  = (const int*)  d_in[1];
  const float* W0  = (const float*)d_in[2];
  const float* as0 = (const float*)d_in[3];
  const float* ad0 = (const float*)d_in[4];
  const float* b0  = (const float*)d_in[5];
  const float* W1  = (const float*)d_in[6];
  const float* as1 = (const float*)d_in[7];
  const float* ad1 = (const float*)d_in[8];
  const float* b1  = (const float*)d_in[9];
  const float* W2  = (const float*)d_in[10];
  const float* as2 = (const float*)d_in[11];
  const float* ad2 = (const float*)d_in[12];
  const float* b2  = (const float*)d_in[13];

  int N = in_sizes[0] / 2;
  int E = in_sizes[1] / 2;
  const int* src = ei;
  const int* dst = ei + E;

  char* ws = (char*)d_ws;
  size_t off = 0;
  auto alc = [&](size_t bytes){ size_t o = off; off += (bytes + 255) & ~(size_t)255; return o; };
  int*   deg    = (int*)  (ws + alc((size_t)N * 4));
  int*   rowptr = (int*)  (ws + alc((size_t)(N + 1) * 4));
  int*   cursor = (int*)  (ws + alc((size_t)N * 4));
  int*   ssrc   = (int*)  (ws + alc((size_t)(E + N) * 4));
  float* bufA   = (float*)(ws + alc((size_t)N * 256 * 4));   // h1
  float* bufB   = (float*)(ws + alc((size_t)N * 256 * 4));   // x1
  float* es1    = (float*)(ws + alc((size_t)N * 4 * 4));
  float* ed1    = (float*)(ws + alc((size_t)N * 4 * 4));
  float* es0    = (float*)(ws + alc((size_t)N * 4 * 4));
  float* ed0    = (float*)(ws + alc((size_t)N * 4 * 4));
  float* h2     = (float*)(ws + alc((size_t)N * 2 * 4));
  float* es2    = (float*)(ws + alc((size_t)N * 4));
  float* ed2    = (float*)(ws + alc((size_t)N * 4));
  unsigned short* wht = (unsigned short*)(ws + alc((size_t)256 * 256 * 2));
  unsigned short* wlt = (unsigned short*)(ws + alc((size_t)256 * 256 * 2));
  float* agg2   = (float*)(ws + alc((size_t)N * 8 * 4));
  float* vs     = (float*)(ws + alc(16 * 4));
  float* out    = (float*)d_out;

  // CSR build + weight prep
  k_init_deg<<<(N + 255)/256, 256, 0, stream>>>(deg, N);
  k_hist    <<<(E + 255)/256, 256, 0, stream>>>(dst, E, deg);
  k_scan    <<<1, 1024, 0, stream>>>(deg, rowptr, N);
  k_selfloop<<<(N + 255)/256, 256, 0, stream>>>(rowptr, ssrc, cursor, N);
  k_scatter <<<(E + 255)/256, 256, 0, stream>>>(src, dst, E, cursor, ssrc);
  k_w1conv  <<<256, 256, 0, stream>>>(W1, wht, wlt);
  k_prep_vs <<<1, 64, 0, stream>>>(W0, as0, ad0, vs);

  // layer 0 (collapsed to 2-dim aggregation, all f32)
  k_es0  <<<(N + 255)/256, 256, 0, stream>>>(x, vs, es0, ed0, N);
  k_edge0<<<(N + 3)/4, 256, 0, stream>>>(x, es0, ed0, rowptr, ssrc, agg2, N);
  k_mid2 <<<(N + 3)/4, 256, 0, stream>>>(agg2, W0, b0, bufB, N);

  // layer 1: GEMM BEFORE aggregation (error-averaging), then gather+aggregate
  k_l1_mfma<<<(N + 63)/64, 256, 0, stream>>>(bufB, wht, wlt, as1, ad1, bufA, es1, ed1, N);
  k_edge1  <<<(N + 3)/4, 256, 0, stream>>>(bufA, es1, ed1, rowptr, ssrc, b1, W2, as2, ad2,
                                           h2, es2, ed2, N);

  // layer 2 (2-dim aggregation)
  k_edge2<<<(N + 3)/4, 256, 0, stream>>>(h2, es2, ed2, rowptr, ssrc, b2, out, N);
}